// Round 3
// baseline (162.990 us; speedup 1.0000x reference)
//
#include <hip/hip_runtime.h>
#include <stdint.h>

#define B_  4
#define NQ_ 2048
#define NP_ 8192
#define D_  256
#define F_  40
#define K_  16

// ---------------- Kernel 1: hash codes -------------------------------------
__global__ __launch_bounds__(256) void hash_kernel(
    const float* __restrict__ qp, const float* __restrict__ pp,
    const float* __restrict__ proj, uint64_t* __restrict__ qcodes,
    uint64_t* __restrict__ pcodes) {
  __shared__ float tile[64 * 257];
  int t = threadIdx.x;
  int v0 = blockIdx.x * 64;  // first vector in concat [queries; points] space
  bool isQ = v0 < B_ * NQ_;
  const float* src =
      isQ ? (qp + (size_t)v0 * D_) : (pp + (size_t)(v0 - B_ * NQ_) * D_);

#pragma unroll 8
  for (int i = 0; i < 64; ++i) tile[i * 257 + t] = src[i * 256 + t];
  __syncthreads();

  int lane = t & 63, w = t >> 6;
  int fbase = __builtin_amdgcn_readfirstlane(w * 10);
  const float* pj = proj + (size_t)fbase * 256;

  float acc[10];
#pragma unroll
  for (int f = 0; f < 10; ++f) acc[f] = 0.0f;
#pragma unroll 4
  for (int d = 0; d < 256; ++d) {
    float x = tile[lane * 257 + d];  // bank (lane+d)%32 -> 2-way, free
#pragma unroll
    for (int f = 0; f < 10; ++f) acc[f] = fmaf(x, pj[f * 256 + d], acc[f]);
  }
  unsigned bits = 0;
#pragma unroll
  for (int f = 0; f < 10; ++f)
    if (acc[f] > 0.0f) bits |= 1u << f;

  __syncthreads();
  unsigned short* cb = (unsigned short*)tile;
  cb[lane * 4 + w] = (unsigned short)bits;
  __syncthreads();
  if (w == 0) {
    uint64_t code = (uint64_t)cb[lane * 4 + 0] |
                    ((uint64_t)cb[lane * 4 + 1] << 10) |
                    ((uint64_t)cb[lane * 4 + 2] << 20) |
                    ((uint64_t)cb[lane * 4 + 3] << 30);
    int gv = v0 + lane;
    if (isQ) qcodes[gv] = code;
    else pcodes[gv - B_ * NQ_] = code;
  }
}

// ---------------- Kernel 2: exact top-16 by (dist, index) -------------------
// v3 (retry — round-2 bench died on container acquisition, not the kernel):
// single LDS scan. Pass 1 computes each distance ONCE, caches dc = min(d,15)
// as a nibble (128 pts/lane -> 16 VGPRs), and histograms rc = med3(d-8,0,7):
// bin0 merges d<=8, bin7 merges d>=15 (no nb counter, no cndmask range
// guards). Threshold found at r in [1,6] gives exact n_lt = #{d<t} with
// t in [9,14]; then pass 3 is a zero-LDS, zero-popcount nibble scan with
// pair-ordered ballot compaction and an early-skipped eq phase.
// r in {0,7} (prob ~0) -> exact cold fallback = original 3-pass.
__global__ __launch_bounds__(1024) void select_kernel(
    const uint64_t* __restrict__ qcodes, const uint64_t* __restrict__ pcodes,
    float* __restrict__ outIdx, float* __restrict__ outDist) {
  __shared__ ulonglong2 ldsP2[NP_ / 2];  // 64 KB
  __shared__ unsigned keybuf[16][K_];
  uint64_t* ldsP = (uint64_t*)ldsP2;

  int tid = threadIdx.x;
  int bb = blockIdx.x >> 7;  // 128 blocks per batch
  const ulonglong2* pb2 = (const ulonglong2*)(pcodes + (size_t)bb * NP_);
  for (int i = tid; i < NP_ / 2; i += 1024) ldsP2[i] = pb2[i];  // dwordx4
  __syncthreads();

  int w = tid >> 6, lane = tid & 63;
  int qg = blockIdx.x * 16 + w;  // global query id
  uint64_t qc = qcodes[qg];
  const uint64_t M = 0x00FF00FF00FF00FFull;

  // ---- Pass 1: distances once; nibble cache + merged-bin histogram ----
  // Lane's i-th point (i = 2*j2+slot): p = j2*128 + 2*lane + slot.
  unsigned pack[16];
#pragma unroll
  for (int i = 0; i < 16; ++i) pack[i] = 0;
  uint64_t cf = 0;
#pragma unroll
  for (int j2 = 0; j2 < 64; ++j2) {
    ulonglong2 pc = ldsP2[j2 * 64 + lane];
    unsigned d0 = (unsigned)__popcll(qc ^ pc.x);
    unsigned d1 = (unsigned)__popcll(qc ^ pc.y);
    unsigned c0 = d0 < 15u ? d0 : 15u;
    unsigned c1 = d1 < 15u ? d1 : 15u;
    pack[j2 >> 2] |= (c0 << (((2 * j2) & 7) * 4)) | (c1 << (((2 * j2 + 1) & 7) * 4));
    int r0 = (int)d0 - 8; r0 = r0 < 0 ? 0 : (r0 > 7 ? 7 : r0);  // v_med3
    int r1 = (int)d1 - 8; r1 = r1 < 0 ? 0 : (r1 > 7 ? 7 : r1);
    cf += (1ull << (r0 << 3)) + (1ull << (r1 << 3));  // bytes, <=128/lane: safe
    if ((j2 & 7) == 7) __builtin_amdgcn_sched_barrier(0);  // cap load hoisting
  }
  uint64_t e = cf & M, o = (cf >> 8) & M;
#pragma unroll
  for (int s = 1; s < 64; s <<= 1) {
    e += __shfl_xor(e, s);
    o += __shfl_xor(o, s);
  }

  int t = 0;
  unsigned n_lt = 0;
  int rfound = -1;
  {
    unsigned cum = 0;
#pragma unroll
    for (int r = 0; r < 8; ++r) {
      unsigned c = (unsigned)(((r & 1) ? o : e) >> ((r >> 1) * 16)) & 0xFFFFu;
      if (rfound < 0 && cum + c >= K_) { rfound = r; t = 8 + r; n_lt = cum; }
      cum += c;
    }
  }
  uint64_t lmask = (1ull << lane) - 1;

  if (rfound >= 1 && rfound <= 6) {
    // ---- Pass 3 (fast): nibble scan, pair-ordered collection ----
    unsigned r_need = K_ - n_lt;
    unsigned cl = 0, ce = 0;
    unsigned ut = (unsigned)t;
#pragma unroll
    for (int j2 = 0; j2 < 64; ++j2) {
      unsigned pw = pack[j2 >> 2];
      unsigned d0 = (pw >> (((2 * j2) & 7) * 4)) & 0xFu;
      unsigned d1 = (pw >> (((2 * j2 + 1) & 7) * 4)) & 0xFu;
      int p0 = j2 * 128 + 2 * lane;
      uint64_t m0 = __ballot(d0 < ut);
      uint64_t m1 = __ballot(d1 < ut);
      if (m0 | m1) {
        unsigned base =
            cl + (unsigned)__popcll(m0 & lmask) + (unsigned)__popcll(m1 & lmask);
        if (d0 < ut) keybuf[w][base] = (d0 << 13) | (unsigned)p0;
        if (d1 < ut)
          keybuf[w][base + (unsigned)((m0 >> lane) & 1)] =
              (d1 << 13) | (unsigned)(p0 + 1);
        cl += (unsigned)__popcll(m0) + (unsigned)__popcll(m1);
      }
      if (ce < r_need) {  // wave-uniform: skipped once eq quota filled
        uint64_t q0 = __ballot(d0 == ut);
        uint64_t q1 = __ballot(d1 == ut);
        if (q0 | q1) {
          unsigned b2 =
              ce + (unsigned)__popcll(q0 & lmask) + (unsigned)__popcll(q1 & lmask);
          unsigned pos1 = b2 + (unsigned)((q0 >> lane) & 1);
          if (d0 == ut && b2 < r_need)
            keybuf[w][n_lt + b2] = (ut << 13) | (unsigned)p0;
          if (d1 == ut && pos1 < r_need)
            keybuf[w][n_lt + pos1] = (ut << 13) | (unsigned)(p0 + 1);
          ce += (unsigned)__popcll(q0) + (unsigned)__popcll(q1);
        }
      }
    }
  } else {
    // ---- Exact fallback (cold, prob ~0): original coarse+fine+collect ----
    uint64_t c8 = 0;
#pragma unroll 4
    for (int j = 0; j < 64; ++j) {
      ulonglong2 pc = ldsP2[j * 64 + lane];
      int d0 = __popcll(qc ^ pc.x);
      int d1 = __popcll(qc ^ pc.y);
      c8 += (1ull << (d0 & 56)) + (1ull << (d1 & 56));  // (d>>3)*8 == d&56
    }
    uint64_t e2 = c8 & M, o2 = (c8 >> 8) & M;
#pragma unroll
    for (int s = 1; s < 64; s <<= 1) {
      e2 += __shfl_xor(e2, s);
      o2 += __shfl_xor(o2, s);
    }
    int Bb = 0;
    unsigned nbefore = 0, cum = 0;
    bool found = false;
#pragma unroll
    for (int k2 = 0; k2 < 6; ++k2) {
      unsigned c = (unsigned)(((k2 & 1) ? o2 : e2) >> ((k2 >> 1) * 16)) & 0xFFFFu;
      if (!found && cum + c >= K_) { Bb = k2; nbefore = cum; found = true; }
      cum += c;
    }
    int base = Bb * 8;
    uint64_t cff = 0;
#pragma unroll 4
    for (int j = 0; j < 64; ++j) {
      ulonglong2 pc = ldsP2[j * 64 + lane];
      unsigned r0 = (unsigned)(__popcll(qc ^ pc.x) - base);
      unsigned r1 = (unsigned)(__popcll(qc ^ pc.y) - base);
      if (r0 < 8u) cff += 1ull << (r0 << 3);
      if (r1 < 8u) cff += 1ull << (r1 << 3);
    }
    uint64_t ef = cff & M, of = (cff >> 8) & M;
#pragma unroll
    for (int s = 1; s < 64; s <<= 1) {
      ef += __shfl_xor(ef, s);
      of += __shfl_xor(of, s);
    }
    unsigned cum2 = nbefore;
    bool f2 = false;
#pragma unroll
    for (int r = 0; r < 8; ++r) {
      unsigned c = (unsigned)(((r & 1) ? of : ef) >> ((r >> 1) * 16)) & 0xFFFFu;
      if (!f2 && cum2 + c >= K_) { t = base + r; n_lt = cum2; f2 = true; }
      cum2 += c;
    }
    unsigned r_need = K_ - n_lt;
    unsigned cl = 0, ce = 0;
    for (int j = 0; j < 128; ++j) {
      int p = j * 64 + lane;
      int d = __popcll(qc ^ ldsP[p]);
      if (__any(d <= t)) {
        bool blt = (d < t), beq = (d == t);
        uint64_t mlt = __ballot(blt), meq = __ballot(beq);
        if (blt)
          keybuf[w][cl + (unsigned)__popcll(mlt & lmask)] =
              ((unsigned)d << 13) | (unsigned)p;
        if (beq) {
          unsigned pos = ce + (unsigned)__popcll(meq & lmask);
          if (pos < r_need)
            keybuf[w][n_lt + pos] = ((unsigned)d << 13) | (unsigned)p;
        }
        cl += (unsigned)__popcll(mlt);
        ce += (unsigned)__popcll(meq);
      }
    }
  }
  __syncthreads();

  // ---- rank-sort the 16 keys (distinct: idx embedded) and emit ----
  if (lane < K_) {
    unsigned my = keybuf[w][lane];
    int rank = 0;
#pragma unroll
    for (int jj = 0; jj < K_; ++jj) rank += (keybuf[w][jj] < my) ? 1 : 0;
    int off = qg * K_ + rank;
    outIdx[off]  = (float)(my & 8191u);  // index
    outDist[off] = (float)(my >> 13);    // distance
  }
}

extern "C" void kernel_launch(void* const* d_in, const int* in_sizes, int n_in,
                              void* d_out, int out_size, void* d_ws, size_t ws_size,
                              hipStream_t stream) {
  const float* qp   = (const float*)d_in[0];
  const float* pp   = (const float*)d_in[1];
  const float* proj = (const float*)d_in[2];
  // d_in[3] is k (always 16) — hardcoded.

  uint64_t* pcodes = (uint64_t*)d_ws;            // B*NP u64
  uint64_t* qcodes = pcodes + (size_t)B_ * NP_;  // B*NQ u64

  float* outIdx  = (float*)d_out;                   // B*NQ*K indices (as float)
  float* outDist = outIdx + (size_t)B_ * NQ_ * K_;  // B*NQ*K distances

  int total_vecs = B_ * (NQ_ + NP_);  // 40960
  hash_kernel<<<total_vecs / 64, 256, 0, stream>>>(qp, pp, proj, qcodes, pcodes);
  select_kernel<<<B_ * NQ_ / 16, 1024, 0, stream>>>(qcodes, pcodes, outIdx, outDist);
}

// Round 5
// 150.106 us; speedup vs baseline: 1.0858x; 1.0858x over previous
//
#include <hip/hip_runtime.h>
#include <stdint.h>

#define B_  4
#define NQ_ 2048
#define NP_ 8192
#define D_  256
#define F_  40
#define K_  16

// ---------------- Kernel 1: hash codes -------------------------------------
__global__ __launch_bounds__(256) void hash_kernel(
    const float* __restrict__ qp, const float* __restrict__ pp,
    const float* __restrict__ proj, uint64_t* __restrict__ qcodes,
    uint64_t* __restrict__ pcodes) {
  __shared__ float tile[64 * 257];
  int t = threadIdx.x;
  int v0 = blockIdx.x * 64;  // first vector in concat [queries; points] space
  bool isQ = v0 < B_ * NQ_;
  const float* src =
      isQ ? (qp + (size_t)v0 * D_) : (pp + (size_t)(v0 - B_ * NQ_) * D_);

#pragma unroll 8
  for (int i = 0; i < 64; ++i) tile[i * 257 + t] = src[i * 256 + t];
  __syncthreads();

  int lane = t & 63, w = t >> 6;
  int fbase = __builtin_amdgcn_readfirstlane(w * 10);
  const float* pj = proj + (size_t)fbase * 256;

  float acc[10];
#pragma unroll
  for (int f = 0; f < 10; ++f) acc[f] = 0.0f;
#pragma unroll 4
  for (int d = 0; d < 256; ++d) {
    float x = tile[lane * 257 + d];  // bank (lane+d)%32 -> 2-way, free
#pragma unroll
    for (int f = 0; f < 10; ++f) acc[f] = fmaf(x, pj[f * 256 + d], acc[f]);
  }
  unsigned bits = 0;
#pragma unroll
  for (int f = 0; f < 10; ++f)
    if (acc[f] > 0.0f) bits |= 1u << f;

  __syncthreads();
  unsigned short* cb = (unsigned short*)tile;
  cb[lane * 4 + w] = (unsigned short)bits;
  __syncthreads();
  if (w == 0) {
    uint64_t code = (uint64_t)cb[lane * 4 + 0] |
                    ((uint64_t)cb[lane * 4 + 1] << 10) |
                    ((uint64_t)cb[lane * 4 + 2] << 20) |
                    ((uint64_t)cb[lane * 4 + 3] << 30);
    int gv = v0 + lane;
    if (isQ) qcodes[gv] = code;
    else pcodes[gv - B_ * NQ_] = code;
  }
}

// ---------------- Kernel 2: exact top-16 by (dist, index) -------------------
// v4 (retry #2 — round-4 bench died on container acquisition again; same
// infra error as round 2 which cleared on identical resubmit):
// nibble cache moved VGPR->LDS (v3 spilled: VGPR capped at 64 for
// occupancy, pack[16] went to scratch -> 56MB writes). Codes are read
// straight from global (64KB/batch, L2/L3-resident, shared by all blocks)
// instead of an LDS tile; LDS instead holds the per-wave 4-bit distance
// cache (8192 x 4b = 4KB/wave). Each wave touches only its own LDS region
// -> ZERO __syncthreads in the kernel. 512-thread blocks, launch_bounds
// (512,8) pins VGPR<=64 -> 4 blocks/CU = 32 waves/CU.
// Pass 1: stream codes (dwordx4, coalesced), distances ONCE, cache
// dc=min(d,15) nibbles (1 ds_write_b32 per 4 iters), histogram
// rc=med3(d-8,0,7). Threshold r in [1,6] -> exact n_lt, t in [9,14];
// pass 3 re-reads nibbles (16 ds_read_b32/lane) with the v3-verified
// pair-ordered ballot compaction. r in {0,7} (prob ~0) -> exact cold
// fallback (global re-scan, original 3-pass).
__global__ __launch_bounds__(512, 8) void select_kernel(
    const uint64_t* __restrict__ qcodes, const uint64_t* __restrict__ pcodes,
    float* __restrict__ outIdx, float* __restrict__ outDist) {
  __shared__ unsigned nib[8 * 1024];  // 32 KB: 8 waves x 4KB nibble cache
  __shared__ unsigned keybuf[8][K_];

  int tid = threadIdx.x;
  int w = tid >> 6, lane = tid & 63;
  int qg = blockIdx.x * 8 + w;  // global query id
  int bb = blockIdx.x >> 8;     // 256 blocks per batch
  const ulonglong2* pb2 = (const ulonglong2*)(pcodes + (size_t)bb * NP_);
  uint64_t qc = qcodes[qg];
  unsigned* nibw = nib + w * 1024;
  const uint64_t M = 0x00FF00FF00FF00FFull;

  // ---- Pass 1: stream codes from L2; nibble cache + merged-bin hist ----
  // Lane's points: p = j2*128 + 2*lane + slot. Nibbles of 4 j2-groups
  // accumulate into one dword -> nibw[lane + 64*(j2>>2)].
  uint64_t cf = 0;
  unsigned accum = 0;
#pragma unroll 4
  for (int j2 = 0; j2 < 64; ++j2) {
    ulonglong2 pc = pb2[j2 * 64 + lane];  // coalesced 16B, L2-hot
    unsigned d0 = (unsigned)__popcll(qc ^ pc.x);
    unsigned d1 = (unsigned)__popcll(qc ^ pc.y);
    unsigned c0 = d0 < 15u ? d0 : 15u;
    unsigned c1 = d1 < 15u ? d1 : 15u;
    accum |= (c0 | (c1 << 4)) << (8 * (j2 & 3));
    int r0 = (int)d0 - 8; r0 = r0 < 0 ? 0 : (r0 > 7 ? 7 : r0);  // v_med3
    int r1 = (int)d1 - 8; r1 = r1 < 0 ? 0 : (r1 > 7 ? 7 : r1);
    cf += (1ull << (r0 << 3)) + (1ull << (r1 << 3));  // bytes <=128: safe
    if ((j2 & 3) == 3) {
      nibw[lane + 64 * (j2 >> 2)] = accum;  // bank lane%32: 2-way, free
      accum = 0;
    }
  }
  uint64_t e = cf & M, o = (cf >> 8) & M;
#pragma unroll
  for (int s = 1; s < 64; s <<= 1) {
    e += __shfl_xor(e, s);
    o += __shfl_xor(o, s);
  }

  int t = 0;
  unsigned n_lt = 0;
  int rfound = -1;
  {
    unsigned cum = 0;
#pragma unroll
    for (int r = 0; r < 8; ++r) {
      unsigned c = (unsigned)(((r & 1) ? o : e) >> ((r >> 1) * 16)) & 0xFFFFu;
      if (rfound < 0 && cum + c >= K_) { rfound = r; t = 8 + r; n_lt = cum; }
      cum += c;
    }
  }
  uint64_t lmask = (1ull << lane) - 1;

  if (rfound >= 1 && rfound <= 6) {
    // ---- Pass 3 (fast): LDS nibble scan, pair-ordered collection ----
    unsigned r_need = K_ - n_lt;
    unsigned cl = 0, ce = 0;
    unsigned ut = (unsigned)t;
#pragma unroll 4
    for (int k = 0; k < 16; ++k) {
      unsigned dw = nibw[lane + 64 * k];
#pragma unroll
      for (int b = 0; b < 4; ++b) {
        unsigned d0 = (dw >> (8 * b)) & 0xFu;
        unsigned d1 = (dw >> (8 * b + 4)) & 0xFu;
        int p0 = (4 * k + b) * 128 + 2 * lane;
        uint64_t m0 = __ballot(d0 < ut);
        uint64_t m1 = __ballot(d1 < ut);
        if (m0 | m1) {
          unsigned base = cl + (unsigned)__popcll(m0 & lmask) +
                          (unsigned)__popcll(m1 & lmask);
          if (d0 < ut) keybuf[w][base] = (d0 << 13) | (unsigned)p0;
          if (d1 < ut)
            keybuf[w][base + (unsigned)((m0 >> lane) & 1)] =
                (d1 << 13) | (unsigned)(p0 + 1);
          cl += (unsigned)__popcll(m0) + (unsigned)__popcll(m1);
        }
        if (ce < r_need) {  // wave-uniform: skipped once eq quota filled
          uint64_t q0 = __ballot(d0 == ut);
          uint64_t q1 = __ballot(d1 == ut);
          if (q0 | q1) {
            unsigned b2 = ce + (unsigned)__popcll(q0 & lmask) +
                          (unsigned)__popcll(q1 & lmask);
            unsigned pos1 = b2 + (unsigned)((q0 >> lane) & 1);
            if (d0 == ut && b2 < r_need)
              keybuf[w][n_lt + b2] = (ut << 13) | (unsigned)p0;
            if (d1 == ut && pos1 < r_need)
              keybuf[w][n_lt + pos1] = (ut << 13) | (unsigned)(p0 + 1);
            ce += (unsigned)__popcll(q0) + (unsigned)__popcll(q1);
          }
        }
      }
    }
  } else {
    // ---- Exact fallback (cold, prob ~0): global re-scan, 3-pass ----
    const uint64_t* pbl = pcodes + (size_t)bb * NP_;
    uint64_t c8 = 0;
#pragma unroll 4
    for (int j = 0; j < 64; ++j) {
      ulonglong2 pc = pb2[j * 64 + lane];
      int d0 = __popcll(qc ^ pc.x);
      int d1 = __popcll(qc ^ pc.y);
      c8 += (1ull << (d0 & 56)) + (1ull << (d1 & 56));  // (d>>3)*8 == d&56
    }
    uint64_t e2 = c8 & M, o2 = (c8 >> 8) & M;
#pragma unroll
    for (int s = 1; s < 64; s <<= 1) {
      e2 += __shfl_xor(e2, s);
      o2 += __shfl_xor(o2, s);
    }
    int Bb = 0;
    unsigned nbefore = 0, cum = 0;
    bool found = false;
#pragma unroll
    for (int k2 = 0; k2 < 6; ++k2) {
      unsigned c = (unsigned)(((k2 & 1) ? o2 : e2) >> ((k2 >> 1) * 16)) & 0xFFFFu;
      if (!found && cum + c >= K_) { Bb = k2; nbefore = cum; found = true; }
      cum += c;
    }
    int base = Bb * 8;
    uint64_t cff = 0;
#pragma unroll 4
    for (int j = 0; j < 64; ++j) {
      ulonglong2 pc = pb2[j * 64 + lane];
      unsigned r0 = (unsigned)(__popcll(qc ^ pc.x) - base);
      unsigned r1 = (unsigned)(__popcll(qc ^ pc.y) - base);
      if (r0 < 8u) cff += 1ull << (r0 << 3);
      if (r1 < 8u) cff += 1ull << (r1 << 3);
    }
    uint64_t ef = cff & M, of = (cff >> 8) & M;
#pragma unroll
    for (int s = 1; s < 64; s <<= 1) {
      ef += __shfl_xor(ef, s);
      of += __shfl_xor(of, s);
    }
    unsigned cum2 = nbefore;
    bool f2 = false;
#pragma unroll
    for (int r = 0; r < 8; ++r) {
      unsigned c = (unsigned)(((r & 1) ? of : ef) >> ((r >> 1) * 16)) & 0xFFFFu;
      if (!f2 && cum2 + c >= K_) { t = base + r; n_lt = cum2; f2 = true; }
      cum2 += c;
    }
    unsigned r_need = K_ - n_lt;
    unsigned cl = 0, ce = 0;
    for (int j = 0; j < 128; ++j) {
      int p = j * 64 + lane;
      int d = __popcll(qc ^ pbl[p]);
      if (__any(d <= t)) {
        bool blt = (d < t), beq = (d == t);
        uint64_t mlt = __ballot(blt), meq = __ballot(beq);
        if (blt)
          keybuf[w][cl + (unsigned)__popcll(mlt & lmask)] =
              ((unsigned)d << 13) | (unsigned)p;
        if (beq) {
          unsigned pos = ce + (unsigned)__popcll(meq & lmask);
          if (pos < r_need)
            keybuf[w][n_lt + pos] = ((unsigned)d << 13) | (unsigned)p;
        }
        cl += (unsigned)__popcll(mlt);
        ce += (unsigned)__popcll(meq);
      }
    }
  }

  // ---- rank-sort the 16 keys (distinct: idx embedded) and emit ----
  // keybuf[w] written and read by the SAME wave: no block sync needed.
  if (lane < K_) {
    unsigned my = keybuf[w][lane];
    int rank = 0;
#pragma unroll
    for (int jj = 0; jj < K_; ++jj) rank += (keybuf[w][jj] < my) ? 1 : 0;
    int off = qg * K_ + rank;
    outIdx[off]  = (float)(my & 8191u);  // index
    outDist[off] = (float)(my >> 13);    // distance
  }
}

extern "C" void kernel_launch(void* const* d_in, const int* in_sizes, int n_in,
                              void* d_out, int out_size, void* d_ws, size_t ws_size,
                              hipStream_t stream) {
  const float* qp   = (const float*)d_in[0];
  const float* pp   = (const float*)d_in[1];
  const float* proj = (const float*)d_in[2];
  // d_in[3] is k (always 16) — hardcoded.

  uint64_t* pcodes = (uint64_t*)d_ws;            // B*NP u64
  uint64_t* qcodes = pcodes + (size_t)B_ * NP_;  // B*NQ u64

  float* outIdx  = (float*)d_out;                   // B*NQ*K indices (as float)
  float* outDist = outIdx + (size_t)B_ * NQ_ * K_;  // B*NQ*K distances

  int total_vecs = B_ * (NQ_ + NP_);  // 40960
  hash_kernel<<<total_vecs / 64, 256, 0, stream>>>(qp, pp, proj, qcodes, pcodes);
  select_kernel<<<B_ * NQ_ / 8, 512, 0, stream>>>(qcodes, pcodes, outIdx, outDist);
}

// Round 6
// 139.057 us; speedup vs baseline: 1.1721x; 1.0795x over previous
//
#include <hip/hip_runtime.h>
#include <stdint.h>

#define B_  4
#define NQ_ 2048
#define NP_ 8192
#define D_  256
#define F_  40
#define K_  16

// ---------------- Kernel 1: hash codes -------------------------------------
// v5: occupancy fix. 512-thread blocks (8 waves), wave w computes features
// [5w,5w+5) for vector = lane; same 64x257 fp32 tile (read bank 2-way =
// free) -> 2 blocks/CU x 8 waves = 4 waves/SIMD (was 2). Staging widened to
// 8 float4 loads/thread (wave covers one row/iter, coalesced 1KB), all 8 in
// flight, instead of 64 latency-chained dwords. Per-feature accumulation
// stays sequential d=0..255 (sign/bit-exact vs reference); bit order is a
// fixed permutation applied identically to qcodes and pcodes -> distances
// unchanged.
__global__ __launch_bounds__(512) void hash_kernel(
    const float* __restrict__ qp, const float* __restrict__ pp,
    const float* __restrict__ proj, uint64_t* __restrict__ qcodes,
    uint64_t* __restrict__ pcodes) {
  __shared__ float tile[64 * 257];
  int t = threadIdx.x;
  int v0 = blockIdx.x * 64;  // first vector in concat [queries; points] space
  bool isQ = v0 < B_ * NQ_;  // B*NQ = 8192 = 128 blocks: clean split
  const float* src =
      isQ ? (qp + (size_t)v0 * D_) : (pp + (size_t)(v0 - B_ * NQ_) * D_);
  const float4* src4 = (const float4*)src;  // rows are 1KB-aligned

  // Stage: iter i, thread t covers float4 #(i*512+t) -> row i*8 + (t>>6)
  // (wave-uniform), cols 4*(t&63).. +3. 8 dwordx4 in flight per thread.
#pragma unroll
  for (int i = 0; i < 8; ++i) {
    float4 x = src4[i * 512 + t];
    int r = i * 8 + (t >> 6);
    int c = 4 * (t & 63);
    tile[r * 257 + c + 0] = x.x;  // stride 257 breaks 16B align: b32 writes
    tile[r * 257 + c + 1] = x.y;
    tile[r * 257 + c + 2] = x.z;
    tile[r * 257 + c + 3] = x.w;
  }
  __syncthreads();

  int lane = t & 63, w = t >> 6;  // 8 waves
  int fbase = __builtin_amdgcn_readfirstlane(w * 5);
  const float* pj = proj + (size_t)fbase * 256;

  float acc[5];
#pragma unroll
  for (int f = 0; f < 5; ++f) acc[f] = 0.0f;
#pragma unroll 4
  for (int d = 0; d < 256; ++d) {
    float x = tile[lane * 257 + d];  // bank (lane+d)%32 -> 2-way, free
#pragma unroll
    for (int f = 0; f < 5; ++f) acc[f] = fmaf(x, pj[f * 256 + d], acc[f]);
  }
  unsigned bits = 0;
#pragma unroll
  for (int f = 0; f < 5; ++f)
    if (acc[f] > 0.0f) bits |= 1u << f;

  // Combine the 8 waves' 5-bit chunks per vector (reuse tile LDS).
  __syncthreads();
  unsigned short* cb = (unsigned short*)tile;
  cb[lane * 8 + w] = (unsigned short)bits;
  __syncthreads();
  if (w == 0) {
    uint64_t code = 0;
#pragma unroll
    for (int j = 0; j < 8; ++j)
      code |= (uint64_t)cb[lane * 8 + j] << (5 * j);
    int gv = v0 + lane;
    if (isQ) qcodes[gv] = code;
    else pcodes[gv - B_ * NQ_] = code;
  }
}

// ---------------- Kernel 2: exact top-16 by (dist, index) -------------------
// v4 (unchanged, HW-verified absmax 0.0): nibble cache in LDS (4KB/wave),
// codes streamed from global (64KB/batch, L2-resident), zero __syncthreads,
// launch_bounds(512,8) -> 4 blocks/CU = 32 waves/CU.
// Pass 1: distances ONCE, cache dc=min(d,15) nibbles, histogram
// rc=med3(d-8,0,7). Threshold r in [1,6] -> exact n_lt, t in [9,14];
// pass 3 re-reads nibbles with pair-ordered ballot compaction.
// r in {0,7} (prob ~0) -> exact cold fallback (global re-scan, 3-pass).
__global__ __launch_bounds__(512, 8) void select_kernel(
    const uint64_t* __restrict__ qcodes, const uint64_t* __restrict__ pcodes,
    float* __restrict__ outIdx, float* __restrict__ outDist) {
  __shared__ unsigned nib[8 * 1024];  // 32 KB: 8 waves x 4KB nibble cache
  __shared__ unsigned keybuf[8][K_];

  int tid = threadIdx.x;
  int w = tid >> 6, lane = tid & 63;
  int qg = blockIdx.x * 8 + w;  // global query id
  int bb = blockIdx.x >> 8;     // 256 blocks per batch
  const ulonglong2* pb2 = (const ulonglong2*)(pcodes + (size_t)bb * NP_);
  uint64_t qc = qcodes[qg];
  unsigned* nibw = nib + w * 1024;
  const uint64_t M = 0x00FF00FF00FF00FFull;

  // ---- Pass 1: stream codes from L2; nibble cache + merged-bin hist ----
  uint64_t cf = 0;
  unsigned accum = 0;
#pragma unroll 4
  for (int j2 = 0; j2 < 64; ++j2) {
    ulonglong2 pc = pb2[j2 * 64 + lane];  // coalesced 16B, L2-hot
    unsigned d0 = (unsigned)__popcll(qc ^ pc.x);
    unsigned d1 = (unsigned)__popcll(qc ^ pc.y);
    unsigned c0 = d0 < 15u ? d0 : 15u;
    unsigned c1 = d1 < 15u ? d1 : 15u;
    accum |= (c0 | (c1 << 4)) << (8 * (j2 & 3));
    int r0 = (int)d0 - 8; r0 = r0 < 0 ? 0 : (r0 > 7 ? 7 : r0);  // v_med3
    int r1 = (int)d1 - 8; r1 = r1 < 0 ? 0 : (r1 > 7 ? 7 : r1);
    cf += (1ull << (r0 << 3)) + (1ull << (r1 << 3));  // bytes <=128: safe
    if ((j2 & 3) == 3) {
      nibw[lane + 64 * (j2 >> 2)] = accum;  // bank lane%32: 2-way, free
      accum = 0;
    }
  }
  uint64_t e = cf & M, o = (cf >> 8) & M;
#pragma unroll
  for (int s = 1; s < 64; s <<= 1) {
    e += __shfl_xor(e, s);
    o += __shfl_xor(o, s);
  }

  int t = 0;
  unsigned n_lt = 0;
  int rfound = -1;
  {
    unsigned cum = 0;
#pragma unroll
    for (int r = 0; r < 8; ++r) {
      unsigned c = (unsigned)(((r & 1) ? o : e) >> ((r >> 1) * 16)) & 0xFFFFu;
      if (rfound < 0 && cum + c >= K_) { rfound = r; t = 8 + r; n_lt = cum; }
      cum += c;
    }
  }
  uint64_t lmask = (1ull << lane) - 1;

  if (rfound >= 1 && rfound <= 6) {
    // ---- Pass 3 (fast): LDS nibble scan, pair-ordered collection ----
    unsigned r_need = K_ - n_lt;
    unsigned cl = 0, ce = 0;
    unsigned ut = (unsigned)t;
#pragma unroll 4
    for (int k = 0; k < 16; ++k) {
      unsigned dw = nibw[lane + 64 * k];
#pragma unroll
      for (int b = 0; b < 4; ++b) {
        unsigned d0 = (dw >> (8 * b)) & 0xFu;
        unsigned d1 = (dw >> (8 * b + 4)) & 0xFu;
        int p0 = (4 * k + b) * 128 + 2 * lane;
        uint64_t m0 = __ballot(d0 < ut);
        uint64_t m1 = __ballot(d1 < ut);
        if (m0 | m1) {
          unsigned base = cl + (unsigned)__popcll(m0 & lmask) +
                          (unsigned)__popcll(m1 & lmask);
          if (d0 < ut) keybuf[w][base] = (d0 << 13) | (unsigned)p0;
          if (d1 < ut)
            keybuf[w][base + (unsigned)((m0 >> lane) & 1)] =
                (d1 << 13) | (unsigned)(p0 + 1);
          cl += (unsigned)__popcll(m0) + (unsigned)__popcll(m1);
        }
        if (ce < r_need) {  // wave-uniform: skipped once eq quota filled
          uint64_t q0 = __ballot(d0 == ut);
          uint64_t q1 = __ballot(d1 == ut);
          if (q0 | q1) {
            unsigned b2 = ce + (unsigned)__popcll(q0 & lmask) +
                          (unsigned)__popcll(q1 & lmask);
            unsigned pos1 = b2 + (unsigned)((q0 >> lane) & 1);
            if (d0 == ut && b2 < r_need)
              keybuf[w][n_lt + b2] = (ut << 13) | (unsigned)p0;
            if (d1 == ut && pos1 < r_need)
              keybuf[w][n_lt + pos1] = (ut << 13) | (unsigned)(p0 + 1);
            ce += (unsigned)__popcll(q0) + (unsigned)__popcll(q1);
          }
        }
      }
    }
  } else {
    // ---- Exact fallback (cold, prob ~0): global re-scan, 3-pass ----
    const uint64_t* pbl = pcodes + (size_t)bb * NP_;
    uint64_t c8 = 0;
#pragma unroll 4
    for (int j = 0; j < 64; ++j) {
      ulonglong2 pc = pb2[j * 64 + lane];
      int d0 = __popcll(qc ^ pc.x);
      int d1 = __popcll(qc ^ pc.y);
      c8 += (1ull << (d0 & 56)) + (1ull << (d1 & 56));  // (d>>3)*8 == d&56
    }
    uint64_t e2 = c8 & M, o2 = (c8 >> 8) & M;
#pragma unroll
    for (int s = 1; s < 64; s <<= 1) {
      e2 += __shfl_xor(e2, s);
      o2 += __shfl_xor(o2, s);
    }
    int Bb = 0;
    unsigned nbefore = 0, cum = 0;
    bool found = false;
#pragma unroll
    for (int k2 = 0; k2 < 6; ++k2) {
      unsigned c = (unsigned)(((k2 & 1) ? o2 : e2) >> ((k2 >> 1) * 16)) & 0xFFFFu;
      if (!found && cum + c >= K_) { Bb = k2; nbefore = cum; found = true; }
      cum += c;
    }
    int base = Bb * 8;
    uint64_t cff = 0;
#pragma unroll 4
    for (int j = 0; j < 64; ++j) {
      ulonglong2 pc = pb2[j * 64 + lane];
      unsigned r0 = (unsigned)(__popcll(qc ^ pc.x) - base);
      unsigned r1 = (unsigned)(__popcll(qc ^ pc.y) - base);
      if (r0 < 8u) cff += 1ull << (r0 << 3);
      if (r1 < 8u) cff += 1ull << (r1 << 3);
    }
    uint64_t ef = cff & M, of = (cff >> 8) & M;
#pragma unroll
    for (int s = 1; s < 64; s <<= 1) {
      ef += __shfl_xor(ef, s);
      of += __shfl_xor(of, s);
    }
    unsigned cum2 = nbefore;
    bool f2 = false;
#pragma unroll
    for (int r = 0; r < 8; ++r) {
      unsigned c = (unsigned)(((r & 1) ? of : ef) >> ((r >> 1) * 16)) & 0xFFFFu;
      if (!f2 && cum2 + c >= K_) { t = base + r; n_lt = cum2; f2 = true; }
      cum2 += c;
    }
    unsigned r_need = K_ - n_lt;
    unsigned cl = 0, ce = 0;
    for (int j = 0; j < 128; ++j) {
      int p = j * 64 + lane;
      int d = __popcll(qc ^ pbl[p]);
      if (__any(d <= t)) {
        bool blt = (d < t), beq = (d == t);
        uint64_t mlt = __ballot(blt), meq = __ballot(beq);
        if (blt)
          keybuf[w][cl + (unsigned)__popcll(mlt & lmask)] =
              ((unsigned)d << 13) | (unsigned)p;
        if (beq) {
          unsigned pos = ce + (unsigned)__popcll(meq & lmask);
          if (pos < r_need)
            keybuf[w][n_lt + pos] = ((unsigned)d << 13) | (unsigned)p;
        }
        cl += (unsigned)__popcll(mlt);
        ce += (unsigned)__popcll(meq);
      }
    }
  }

  // ---- rank-sort the 16 keys (distinct: idx embedded) and emit ----
  // keybuf[w] written and read by the SAME wave: no block sync needed.
  if (lane < K_) {
    unsigned my = keybuf[w][lane];
    int rank = 0;
#pragma unroll
    for (int jj = 0; jj < K_; ++jj) rank += (keybuf[w][jj] < my) ? 1 : 0;
    int off = qg * K_ + rank;
    outIdx[off]  = (float)(my & 8191u);  // index
    outDist[off] = (float)(my >> 13);    // distance
  }
}

extern "C" void kernel_launch(void* const* d_in, const int* in_sizes, int n_in,
                              void* d_out, int out_size, void* d_ws, size_t ws_size,
                              hipStream_t stream) {
  const float* qp   = (const float*)d_in[0];
  const float* pp   = (const float*)d_in[1];
  const float* proj = (const float*)d_in[2];
  // d_in[3] is k (always 16) — hardcoded.

  uint64_t* pcodes = (uint64_t*)d_ws;            // B*NP u64
  uint64_t* qcodes = pcodes + (size_t)B_ * NP_;  // B*NQ u64

  float* outIdx  = (float*)d_out;                   // B*NQ*K indices (as float)
  float* outDist = outIdx + (size_t)B_ * NQ_ * K_;  // B*NQ*K distances

  int total_vecs = B_ * (NQ_ + NP_);  // 40960
  hash_kernel<<<total_vecs / 64, 512, 0, stream>>>(qp, pp, proj, qcodes, pcodes);
  select_kernel<<<B_ * NQ_ / 8, 512, 0, stream>>>(qcodes, pcodes, outIdx, outDist);
}